// Round 3
// baseline (1911.268 us; speedup 1.0000x reference)
//
#include <hip/hip_runtime.h>

// Feature dims fixed by the problem
constexpr int FIN = 64;   // input features
constexpr int FH  = 64;   // hidden
constexpr int FO  = 16;   // output

// NOTE: the harness delivers integer inputs as int32 (JAX default x64-off),
// so edge_index is const int*, laid out [2][E] flat: src = ei[e], dst = ei[e+E].

// ---------------------------------------------------------------------------
// Kernel 1: degree histogram. dinv[d] += 1.0f per edge (exact for deg < 2^24).
// ---------------------------------------------------------------------------
__global__ void degree_kernel(const int* __restrict__ ei, int E,
                              float* __restrict__ dinv) {
    int e = blockIdx.x * blockDim.x + threadIdx.x;
    if (e >= E) return;
    int d = ei[e + E];
    unsafeAtomicAdd(&dinv[d], 1.0f);
}

// ---------------------------------------------------------------------------
// Kernel 2: dinv = rsqrt(deg + 1) in place  (+1 = self loop; always > 0)
// ---------------------------------------------------------------------------
__global__ void dinv_kernel(float* __restrict__ dinv, int N) {
    int i = blockIdx.x * blockDim.x + threadIdx.x;
    if (i < N) dinv[i] = rsqrtf(dinv[i] + 1.0f);
}

// ---------------------------------------------------------------------------
// Kernel 3: hs = (x @ W1) * dinv[row]   (pre-scaled hidden pre-activation)
// W1 (64x64 = 16 KB) staged in LDS, 16 rows per block of 256 threads.
// ---------------------------------------------------------------------------
__launch_bounds__(256)
__global__ void gemm1_kernel(const float* __restrict__ x, const float* __restrict__ W1,
                             const float* __restrict__ dinv, float* __restrict__ hs, int N) {
    __shared__ float Ws[FIN * FH];      // 16 KB
    __shared__ float xs[4][FIN];        // 1 KB
    int tid = threadIdx.x;
    for (int i = tid; i < FIN * FH; i += 256) Ws[i] = W1[i];
    int col = tid & 63;      // output feature
    int rs  = tid >> 6;      // 0..3 row sub-slot
    int rowBase = blockIdx.x * 16;
    for (int rr = 0; rr < 16; rr += 4) {
        int row = rowBase + rr + rs;
        __syncthreads();  // protect xs from previous-iteration readers (also fences Ws load)
        xs[rs][col] = (row < N) ? x[(size_t)row * FIN + col] : 0.f;
        __syncthreads();
        float acc = 0.f;
        #pragma unroll
        for (int k = 0; k < FIN; ++k)
            acc = fmaf(xs[rs][k], Ws[k * FH + col], acc);
        if (row < N) hs[(size_t)row * FH + col] = acc * dinv[row];
    }
}

// ---------------------------------------------------------------------------
// Kernel 4: layer-1 edge scatter. One thread per (edge, float4 chunk of 64).
// ---------------------------------------------------------------------------
__global__ void scatter64_kernel(const float* __restrict__ hs,
                                 const int* __restrict__ ei,
                                 float* __restrict__ agg, int E) {
    int idx = blockIdx.x * blockDim.x + threadIdx.x;
    int e = idx >> 4;          // 16 chunks per edge
    int c = idx & 15;
    if (e >= E) return;
    int s = ei[e];
    int d = ei[e + E];
    float4 v = ((const float4*)hs)[(size_t)s * 16 + c];
    float* p = agg + (size_t)d * FH + c * 4;
    unsafeAtomicAdd(p + 0, v.x);
    unsafeAtomicAdd(p + 1, v.y);
    unsafeAtomicAdd(p + 2, v.z);
    unsafeAtomicAdd(p + 3, v.w);
}

// ---------------------------------------------------------------------------
// Kernel 5: finalize layer 1 (self-loop + post-scale + bias + ReLU) fused with
// GEMM2 and layer-2 pre-scale: hs2 = (relu(dinv*(agg1+hs)+b1) @ W2) * dinv
// ---------------------------------------------------------------------------
__launch_bounds__(256)
__global__ void finalize1_kernel(const float* __restrict__ agg1, const float* __restrict__ hs,
                                 const float* __restrict__ dinv, const float* __restrict__ b1,
                                 const float* __restrict__ W2, float* __restrict__ hs2, int N) {
    __shared__ float W2s[FH * FO];        // 4 KB
    __shared__ float h1s[16][FH + 1];     // padded to dodge bank conflicts
    int tid = threadIdx.x;
    for (int i = tid; i < FH * FO; i += 256) W2s[i] = W2[i];
    int rowBase = blockIdx.x * 16;
    int col = tid & 63, rs = tid >> 6;
    #pragma unroll
    for (int rr = 0; rr < 16; rr += 4) {
        int row = rowBase + rr + rs;
        float v = 0.f;
        if (row < N) {
            float di = dinv[row];
            size_t o = (size_t)row * FH + col;
            v = fmaf(di, agg1[o] + hs[o], b1[col]);
            v = fmaxf(v, 0.f);
        }
        h1s[rr + rs][col] = v;
    }
    __syncthreads();
    int r2 = tid >> 4, o = tid & 15;   // 16 rows x 16 out-cols
    int row = rowBase + r2;
    if (row < N) {
        float acc = 0.f;
        #pragma unroll
        for (int j = 0; j < FH; ++j)
            acc = fmaf(h1s[r2][j], W2s[j * FO + o], acc);
        hs2[(size_t)row * FO + o] = acc * dinv[row];
    }
}

// ---------------------------------------------------------------------------
// Kernel 6: layer-2 edge scatter. One thread per (edge, float4 chunk of 16).
// Accumulates directly into d_out (zeroed beforehand).
// ---------------------------------------------------------------------------
__global__ void scatter16_kernel(const float* __restrict__ hs2,
                                 const int* __restrict__ ei,
                                 float* __restrict__ agg, int E) {
    int idx = blockIdx.x * blockDim.x + threadIdx.x;
    int e = idx >> 2;          // 4 chunks per edge
    int c = idx & 3;
    if (e >= E) return;
    int s = ei[e];
    int d = ei[e + E];
    float4 v = ((const float4*)hs2)[(size_t)s * 4 + c];
    float* p = agg + (size_t)d * FO + c * 4;
    unsafeAtomicAdd(p + 0, v.x);
    unsafeAtomicAdd(p + 1, v.y);
    unsafeAtomicAdd(p + 2, v.z);
    unsafeAtomicAdd(p + 3, v.w);
}

// ---------------------------------------------------------------------------
// Kernel 7: finalize layer 2 + log_softmax over 16 classes.
// agg2 aliases out: each thread reads exactly the element it later writes
// (single-owner), so in-place is safe.
// ---------------------------------------------------------------------------
__launch_bounds__(256)
__global__ void finalize2_kernel(const float* __restrict__ agg2, const float* __restrict__ hs2,
                                 const float* __restrict__ dinv, const float* __restrict__ b2,
                                 float* __restrict__ out, int N) {
    int tid = threadIdx.x;
    int r = tid >> 4, o = tid & 15;
    int row = blockIdx.x * 16 + r;
    float v = 0.f;
    if (row < N) {
        size_t off = (size_t)row * FO + o;
        v = fmaf(dinv[row], agg2[off] + hs2[off], b2[o]);
    }
    // max over the 16-lane group (xor distances < 16 stay in-group)
    float m = v;
    #pragma unroll
    for (int s = 8; s >= 1; s >>= 1) m = fmaxf(m, __shfl_xor(m, s, 64));
    float ex = __expf(v - m);
    float sum = ex;
    #pragma unroll
    for (int s = 8; s >= 1; s >>= 1) sum += __shfl_xor(sum, s, 64);
    if (row < N) out[(size_t)row * FO + o] = v - m - __logf(sum);
}

// ---------------------------------------------------------------------------
extern "C" void kernel_launch(void* const* d_in, const int* in_sizes, int n_in,
                              void* d_out, int out_size, void* d_ws, size_t ws_size,
                              hipStream_t stream) {
    const float* x  = (const float*)d_in[0];
    const int*   ei = (const int*)d_in[1];     // int32! (harness integer convention)
    const float* W1 = (const float*)d_in[2];
    const float* b1 = (const float*)d_in[3];
    const float* W2 = (const float*)d_in[4];
    const float* b2 = (const float*)d_in[5];
    float* out = (float*)d_out;

    const int N = in_sizes[0] / FIN;
    const int E = in_sizes[1] / 2;

    char* ws = (char*)d_ws;
    size_t off = 0;
    auto alloc = [&](size_t bytes) -> void* {
        off = (off + 255) & ~(size_t)255;
        void* p = ws + off;
        off += bytes;
        return p;
    };
    float* dinv = (float*)alloc((size_t)N * 4);             //  0.4 MB
    float* hs   = (float*)alloc((size_t)N * FH * 4);        // 25.6 MB
    float* hs2  = (float*)alloc((size_t)N * FO * 4);        //  6.4 MB
    // agg1: in ws if it fits (58 MB total), else reuse the x input buffer
    // (dead after gemm1; harness restores d_in before every timed launch;
    // ws_size is constant per session so this branch is capture-stable).
    size_t agg1_bytes = (size_t)N * FH * 4;
    float* agg1;
    if (ws_size >= off + 256 + agg1_bytes) {
        agg1 = (float*)alloc(agg1_bytes);
    } else {
        agg1 = (float*)x;   // reuse input buffer as scratch
    }
    float* agg2 = out;      // accumulate layer-2 scatter directly into d_out

    hipMemsetAsync(dinv, 0, (size_t)N * 4, stream);

    degree_kernel<<<(E + 255) / 256, 256, 0, stream>>>(ei, E, dinv);
    dinv_kernel<<<(N + 255) / 256, 256, 0, stream>>>(dinv, N);
    gemm1_kernel<<<(N + 15) / 16, 256, 0, stream>>>(x, W1, dinv, hs, N);
    hipMemsetAsync(agg1, 0, agg1_bytes, stream);            // after gemm1 reads x
    {
        long long threads = (long long)E * 16;
        scatter64_kernel<<<(int)((threads + 255) / 256), 256, 0, stream>>>(hs, ei, agg1, E);
    }
    finalize1_kernel<<<(N + 15) / 16, 256, 0, stream>>>(agg1, hs, dinv, b1, W2, hs2, N);
    hipMemsetAsync(agg2, 0, (size_t)N * FO * 4, stream);
    {
        long long threads = (long long)E * 4;
        scatter16_kernel<<<(int)((threads + 255) / 256), 256, 0, stream>>>(hs2, ei, agg2, E);
    }
    finalize2_kernel<<<(N + 15) / 16, 256, 0, stream>>>(agg2, hs2, dinv, b2, out, N);
}

// Round 4
// 421.574 us; speedup vs baseline: 4.5336x; 4.5336x over previous
//
#include <hip/hip_runtime.h>

// Feature dims fixed by the problem
constexpr int FIN = 64;   // input features
constexpr int FH  = 64;   // hidden
constexpr int FO  = 16;   // output

// edge_index arrives as int32 (harness integer convention), flat [2][E]:
// src = ei[e], dst = ei[e + E].

// ---------------------------------------------------------------------------
// Kernel 1: integer in-degree histogram.
// ---------------------------------------------------------------------------
__global__ void degree_kernel(const int* __restrict__ ei, int E,
                              int* __restrict__ degi) {
    int e = blockIdx.x * blockDim.x + threadIdx.x;
    if (e >= E) return;
    atomicAdd(&degi[ei[e + E]], 1);
}

// ---------------------------------------------------------------------------
// Kernel 2: dinv = rsqrt(deg + 1)   (+1 = self loop; always > 0)
// ---------------------------------------------------------------------------
__global__ void dinv_kernel(const int* __restrict__ degi, float* __restrict__ dinv, int N) {
    int i = blockIdx.x * blockDim.x + threadIdx.x;
    if (i < N) dinv[i] = rsqrtf((float)(degi[i] + 1));
}

// ---------------------------------------------------------------------------
// Scan kernels: exclusive prefix sum of degi -> offs (3-phase, 256/block).
// ---------------------------------------------------------------------------
__global__ void scan1_kernel(const int* __restrict__ degi, int* __restrict__ offs,
                             int* __restrict__ bsums, int N) {
    __shared__ int s[256];
    int t = threadIdx.x, i = blockIdx.x * 256 + t;
    int v = (i < N) ? degi[i] : 0;
    s[t] = v;
    __syncthreads();
    for (int d = 1; d < 256; d <<= 1) {
        int u = (t >= d) ? s[t - d] : 0;
        __syncthreads();
        s[t] += u;
        __syncthreads();
    }
    if (i < N) offs[i] = s[t] - v;              // exclusive within block
    if (t == 255) bsums[blockIdx.x] = s[255];   // block total
}

__global__ void scan2_kernel(int* __restrict__ bsums, int nb) {
    __shared__ int s[512];
    int t = threadIdx.x;
    int v = (t < nb) ? bsums[t] : 0;
    s[t] = v;
    __syncthreads();
    for (int d = 1; d < 512; d <<= 1) {
        int u = (t >= d) ? s[t - d] : 0;
        __syncthreads();
        s[t] += u;
        __syncthreads();
    }
    if (t < nb) bsums[t] = s[t] - v;            // exclusive block offsets
}

__global__ void scan3_kernel(int* __restrict__ offs, const int* __restrict__ bsums,
                             int* __restrict__ cursor, int N, int E) {
    int i = blockIdx.x * 256 + threadIdx.x;
    if (i < N) {
        int o = offs[i] + bsums[blockIdx.x];
        offs[i] = o;
        cursor[i] = o;
        if (i == N - 1) offs[N] = E;
    }
}

// ---------------------------------------------------------------------------
// Kernel: fill CSR adjacency (src lists grouped by dst).
// ---------------------------------------------------------------------------
__global__ void fill_csr_kernel(const int* __restrict__ ei, int E,
                                int* __restrict__ cursor, int* __restrict__ csr) {
    int e = blockIdx.x * blockDim.x + threadIdx.x;
    if (e >= E) return;
    int s = ei[e];
    int d = ei[e + E];
    int pos = atomicAdd(&cursor[d], 1);
    csr[pos] = s;
}

// ---------------------------------------------------------------------------
// Kernel: hs = (x @ W1) * dinv[row]   (pre-scaled hidden pre-activation)
// ---------------------------------------------------------------------------
__launch_bounds__(256)
__global__ void gemm1_kernel(const float* __restrict__ x, const float* __restrict__ W1,
                             const float* __restrict__ dinv, float* __restrict__ hs, int N) {
    __shared__ float Ws[FIN * FH];      // 16 KB
    __shared__ float xs[4][FIN];        // 1 KB
    int tid = threadIdx.x;
    for (int i = tid; i < FIN * FH; i += 256) Ws[i] = W1[i];
    int col = tid & 63;
    int rs  = tid >> 6;
    int rowBase = blockIdx.x * 16;
    for (int rr = 0; rr < 16; rr += 4) {
        int row = rowBase + rr + rs;
        __syncthreads();
        xs[rs][col] = (row < N) ? x[(size_t)row * FIN + col] : 0.f;
        __syncthreads();
        float acc = 0.f;
        #pragma unroll
        for (int k = 0; k < FIN; ++k)
            acc = fmaf(xs[rs][k], Ws[k * FH + col], acc);
        if (row < N) hs[(size_t)row * FH + col] = acc * dinv[row];
    }
}

// ---------------------------------------------------------------------------
// Kernel: layer-1 PULL aggregation fused with finalize1 + GEMM2.
// 16 nodes/block; 16 lanes per node, lane owns one float4 chunk of 64 feats.
// h1 = relu(dinv[n]*(sum_{s in N(n)} hs[s] + hs[n]) + b1); hs2 = (h1@W2)*dinv[n]
// ---------------------------------------------------------------------------
__launch_bounds__(256)
__global__ void agg1_gemm2_kernel(const float* __restrict__ hs, const int* __restrict__ csr,
                                  const int* __restrict__ offs, const float* __restrict__ dinv,
                                  const float* __restrict__ b1, const float* __restrict__ W2,
                                  float* __restrict__ hs2, int N) {
    __shared__ float W2s[FH * FO];       // 4 KB
    __shared__ float h1s[16][68];        // 68-float row stride (16B-aligned, non-pow2)
    const float4* hs4 = (const float4*)hs;
    int tid = threadIdx.x;
    for (int i = tid; i < FH * FO; i += 256) W2s[i] = W2[i];
    int g = tid >> 4, l = tid & 15;
    int n = blockIdx.x * 16 + g;
    if (n < N) {
        float4 acc = hs4[(size_t)n * 16 + l];      // self loop (pre-scaled)
        int j = offs[n], end = offs[n + 1];
        for (; j + 1 < end; j += 2) {              // 2 gathers in flight
            int s0 = csr[j], s1 = csr[j + 1];
            float4 a = hs4[(size_t)s0 * 16 + l];
            float4 b = hs4[(size_t)s1 * 16 + l];
            acc.x += a.x + b.x; acc.y += a.y + b.y;
            acc.z += a.z + b.z; acc.w += a.w + b.w;
        }
        if (j < end) {
            float4 a = hs4[(size_t)csr[j] * 16 + l];
            acc.x += a.x; acc.y += a.y; acc.z += a.z; acc.w += a.w;
        }
        float di = dinv[n];
        float4 bb = ((const float4*)b1)[l];
        float4 h;
        h.x = fmaxf(fmaf(di, acc.x, bb.x), 0.f);
        h.y = fmaxf(fmaf(di, acc.y, bb.y), 0.f);
        h.z = fmaxf(fmaf(di, acc.z, bb.z), 0.f);
        h.w = fmaxf(fmaf(di, acc.w, bb.w), 0.f);
        *((float4*)&h1s[g][l * 4]) = h;
    }
    __syncthreads();
    int r = tid >> 4, o = tid & 15;     // 16 rows x 16 out-cols
    int n2 = blockIdx.x * 16 + r;
    if (n2 < N) {
        float acc = 0.f;
        #pragma unroll
        for (int jj = 0; jj < FH; ++jj)
            acc = fmaf(h1s[r][jj], W2s[jj * FO + o], acc);
        hs2[(size_t)n2 * FO + o] = acc * dinv[n2];
    }
}

// ---------------------------------------------------------------------------
// Kernel: layer-2 PULL aggregation fused with bias + log_softmax.
// 16 nodes/block; 16 lanes per node, lane owns one of 16 classes.
// ---------------------------------------------------------------------------
__launch_bounds__(256)
__global__ void agg2_softmax_kernel(const float* __restrict__ hs2, const int* __restrict__ csr,
                                    const int* __restrict__ offs, const float* __restrict__ dinv,
                                    const float* __restrict__ b2, float* __restrict__ out, int N) {
    int tid = threadIdx.x;
    int g = tid >> 4, o = tid & 15;
    int n = blockIdx.x * 16 + g;
    float v = 0.f;
    if (n < N) {
        float acc = hs2[(size_t)n * 16 + o];       // self loop (pre-scaled)
        int j = offs[n], end = offs[n + 1];
        for (; j + 1 < end; j += 2) {
            int s0 = csr[j], s1 = csr[j + 1];
            acc += hs2[(size_t)s0 * 16 + o] + hs2[(size_t)s1 * 16 + o];
        }
        if (j < end) acc += hs2[(size_t)csr[j] * 16 + o];
        v = fmaf(dinv[n], acc, b2[o]);
    }
    // 16-wide softmax reductions (xor distances < 16 stay in-group)
    float m = v;
    #pragma unroll
    for (int s = 8; s >= 1; s >>= 1) m = fmaxf(m, __shfl_xor(m, s, 64));
    float ex = __expf(v - m);
    float sum = ex;
    #pragma unroll
    for (int s = 8; s >= 1; s >>= 1) sum += __shfl_xor(sum, s, 64);
    if (n < N) out[(size_t)n * FO + o] = v - m - __logf(sum);
}

// ---------------------------------------------------------------------------
extern "C" void kernel_launch(void* const* d_in, const int* in_sizes, int n_in,
                              void* d_out, int out_size, void* d_ws, size_t ws_size,
                              hipStream_t stream) {
    const float* x  = (const float*)d_in[0];
    const int*   ei = (const int*)d_in[1];     // int32
    const float* W1 = (const float*)d_in[2];
    const float* b1 = (const float*)d_in[3];
    const float* W2 = (const float*)d_in[4];
    const float* b2 = (const float*)d_in[5];
    float* out = (float*)d_out;

    const int N = in_sizes[0] / FIN;
    const int E = in_sizes[1] / 2;
    const int NB = (N + 255) / 256;   // scan blocks (must be <= 512)

    char* ws = (char*)d_ws;
    size_t off = 0;
    auto alloc = [&](size_t bytes) -> void* {
        off = (off + 255) & ~(size_t)255;
        void* p = ws + off;
        off += bytes;
        return p;
    };
    float* dinv  = (float*)alloc((size_t)N * 4);            //  0.4 MB
    float* hs    = (float*)alloc((size_t)N * FH * 4);       // 25.6 MB
    float* hs2   = (float*)alloc((size_t)N * FO * 4);       //  6.4 MB
    int*   degi  = (int*)  alloc((size_t)N * 4);            //  0.4 MB (reused as cursor)
    int*   offs  = (int*)  alloc((size_t)(N + 1) * 4);      //  0.4 MB
    int*   bsums = (int*)  alloc(512 * 4);
    int*   cursor = degi;  // degi is dead after dinv/scan1; scan3 rewrites it
    // csr (6.4 MB): in ws if it fits, else alias the x input buffer (x is dead
    // after gemm1, which we order before fill_csr; harness restores d_in
    // before every launch; ws_size constant -> capture-stable branch).
    size_t csr_bytes = (size_t)E * 4;
    int* csr;
    if (ws_size >= off + 256 + csr_bytes) {
        csr = (int*)alloc(csr_bytes);
    } else {
        csr = (int*)x;
    }

    hipMemsetAsync(degi, 0, (size_t)N * 4, stream);

    degree_kernel<<<(E + 255) / 256, 256, 0, stream>>>(ei, E, degi);
    dinv_kernel<<<(N + 255) / 256, 256, 0, stream>>>(degi, dinv, N);
    gemm1_kernel<<<(N + 15) / 16, 256, 0, stream>>>(x, W1, dinv, hs, N);   // reads x
    scan1_kernel<<<NB, 256, 0, stream>>>(degi, offs, bsums, N);
    scan2_kernel<<<1, 512, 0, stream>>>(bsums, NB);
    scan3_kernel<<<NB, 256, 0, stream>>>(offs, bsums, cursor, N, E);
    fill_csr_kernel<<<(E + 255) / 256, 256, 0, stream>>>(ei, E, cursor, csr); // may write x
    agg1_gemm2_kernel<<<(N + 15) / 16, 256, 0, stream>>>(hs, csr, offs, dinv, b1, W2, hs2, N);
    agg2_softmax_kernel<<<(N + 15) / 16, 256, 0, stream>>>(hs2, csr, offs, dinv, b2, out, N);
}

// Round 5
// 297.637 us; speedup vs baseline: 6.4215x; 1.4164x over previous
//
#include <hip/hip_runtime.h>

// Feature dims fixed by the problem
constexpr int FIN = 64;   // input features
constexpr int FH  = 64;   // hidden
constexpr int FO  = 16;   // output

// edge_index arrives as int32 (harness integer convention), flat [2][E]:
// src = ei[e], dst = ei[e + E].

// Bucket sort parameters: bucket = dst >> 7 (128 nodes per bucket).
constexpr int BSH   = 7;
constexpr int BW    = 1 << BSH;    // 128 nodes / bucket
constexpr int NBUCK = 1024;        // covers N up to 131072
constexpr int EPB   = 16384;       // edges per binning block

// ---------------------------------------------------------------------------
// Kernel: hs = x @ W1 (UNSCALED; dinv pre-scale fused into bucket_csr later).
// W1 (64x64 = 16 KB) staged in LDS, 16 rows per block of 256 threads.
// ---------------------------------------------------------------------------
__launch_bounds__(256)
__global__ void gemm1_kernel(const float* __restrict__ x, const float* __restrict__ W1,
                             float* __restrict__ hs, int N) {
    __shared__ float Ws[FIN * FH];      // 16 KB
    __shared__ float xs[4][FIN];        // 1 KB
    int tid = threadIdx.x;
    for (int i = tid; i < FIN * FH; i += 256) Ws[i] = W1[i];
    int col = tid & 63;
    int rs  = tid >> 6;
    int rowBase = blockIdx.x * 16;
    for (int rr = 0; rr < 16; rr += 4) {
        int row = rowBase + rr + rs;
        __syncthreads();
        xs[rs][col] = (row < N) ? x[(size_t)row * FIN + col] : 0.f;
        __syncthreads();
        float acc = 0.f;
        #pragma unroll
        for (int k = 0; k < FIN; ++k)
            acc = fmaf(xs[rs][k], Ws[k * FH + col], acc);
        if (row < N) hs[(size_t)row * FH + col] = acc;
    }
}

// ---------------------------------------------------------------------------
// Kernel: bucket histogram (LDS-staged, ~100k global atomics total).
// ---------------------------------------------------------------------------
__launch_bounds__(256)
__global__ void hist_kernel(const int* __restrict__ ei, int E,
                            int* __restrict__ bcnt) {
    __shared__ int lh[NBUCK];
    int t = threadIdx.x;
    for (int i = t; i < NBUCK; i += 256) lh[i] = 0;
    __syncthreads();
    int base = blockIdx.x * EPB;
    int lim  = min(E, base + EPB);
    for (int e = base + t; e < lim; e += 256)
        atomicAdd(&lh[ei[E + e] >> BSH], 1);
    __syncthreads();
    for (int b = t; b < NBUCK; b += 256) {
        int c = lh[b];
        if (c > 0) atomicAdd(&bcnt[b], c);
    }
}

// ---------------------------------------------------------------------------
// Kernel: exclusive scan of bucket counts -> bbase[NBUCK+1], init gcur.
// Single block of 1024 threads. Also writes offs[N] = E.
// ---------------------------------------------------------------------------
__launch_bounds__(1024)
__global__ void bucket_scan_kernel(const int* __restrict__ bcnt, int* __restrict__ bbase,
                                   int* __restrict__ gcur, int* __restrict__ offs,
                                   int N, int E) {
    __shared__ int s[NBUCK];
    int t = threadIdx.x;
    int v = bcnt[t];
    s[t] = v;
    __syncthreads();
    for (int d = 1; d < NBUCK; d <<= 1) {
        int u = (t >= d) ? s[t - d] : 0;
        __syncthreads();
        s[t] += u;
        __syncthreads();
    }
    int ex = s[t] - v;
    bbase[t] = ex;
    gcur[t]  = ex;
    if (t == NBUCK - 1) {
        bbase[NBUCK] = s[t];   // == E
        offs[N] = E;
    }
}

// ---------------------------------------------------------------------------
// Kernel: binning. Each block reserves contiguous per-bucket runs, then writes
// each edge once as packed word src | (dst & 127) << 17 (N < 2^17).
// Runs avg ~84 B -> mostly single-owner cache lines (kills write amplification).
// ---------------------------------------------------------------------------
__launch_bounds__(256)
__global__ void binning_kernel(const int* __restrict__ ei, int E,
                               int* __restrict__ gcur, unsigned* __restrict__ ebuf) {
    __shared__ int lh[NBUCK];
    int t = threadIdx.x;
    for (int i = t; i < NBUCK; i += 256) lh[i] = 0;
    __syncthreads();
    int base = blockIdx.x * EPB;
    int lim  = min(E, base + EPB);
    for (int e = base + t; e < lim; e += 256)
        atomicAdd(&lh[ei[E + e] >> BSH], 1);
    __syncthreads();
    for (int b = t; b < NBUCK; b += 256) {
        int c = lh[b];
        lh[b] = (c > 0) ? atomicAdd(&gcur[b], c) : 0;   // run base -> running cursor
    }
    __syncthreads();
    for (int e = base + t; e < lim; e += 256) {
        int d = ei[E + e];
        int srcv = ei[e];
        int pos = atomicAdd(&lh[d >> BSH], 1);
        ebuf[pos] = (unsigned)srcv | ((unsigned)(d & (BW - 1)) << 17);
    }
}

// ---------------------------------------------------------------------------
// Kernel: per-bucket CSR build + dinv + offs + hs pre-scale.
// One block per bucket; all csr stores land in the block's own contiguous
// region -> single-owner lines -> writeback ~= data size.
// ---------------------------------------------------------------------------
__launch_bounds__(256)
__global__ void bucket_csr_kernel(const unsigned* __restrict__ ebuf,
                                  const int* __restrict__ bbase,
                                  int* __restrict__ csr, int* __restrict__ offs,
                                  float* __restrict__ dinv, float* __restrict__ hs,
                                  int N) {
    __shared__ int cnt[BW], sc[BW], cur[BW];
    __shared__ float dval[BW];
    int t = threadIdx.x;
    int b = blockIdx.x;
    if (t < BW) cnt[t] = 0;
    __syncthreads();
    int beg = bbase[b], end = bbase[b + 1];
    for (int i = beg + t; i < end; i += 256)
        atomicAdd(&cnt[ebuf[i] >> 17], 1);
    __syncthreads();
    if (t < BW) sc[t] = cnt[t];
    __syncthreads();
    for (int d = 1; d < BW; d <<= 1) {
        int u = (t < BW && t >= d) ? sc[t - d] : 0;
        __syncthreads();
        if (t < BW) sc[t] += u;
        __syncthreads();
    }
    int nodeBase = b << BSH;
    if (t < BW) {
        int node = nodeBase + t;
        int ex = beg + sc[t] - cnt[t];
        cur[t] = ex;
        float di = rsqrtf((float)(cnt[t] + 1));
        dval[t] = di;
        if (node < N) {
            offs[node] = ex;
            dinv[node] = di;
        }
    }
    __syncthreads();
    for (int i = beg + t; i < end; i += 256) {
        unsigned w = ebuf[i];
        int pos = atomicAdd(&cur[w >> 17], 1);
        csr[pos] = (int)(w & 0x1FFFF);
    }
    // fused: hs[node] *= dinv[node] (pre-scale for both pull stages)
    int nNodes = min(BW, N - nodeBase);
    float4* h4 = (float4*)hs;
    for (int k = t; k < nNodes * 16; k += 256) {
        int ln = k >> 4, c = k & 15;
        float di = dval[ln];
        size_t idx = (size_t)(nodeBase + ln) * 16 + c;
        float4 v = h4[idx];
        v.x *= di; v.y *= di; v.z *= di; v.w *= di;
        h4[idx] = v;
    }
}

// ---------------------------------------------------------------------------
// Kernel: layer-1 PULL aggregation fused with finalize1 + GEMM2.
// 16 nodes/block; 16 lanes per node, lane owns one float4 chunk of 64 feats.
// ---------------------------------------------------------------------------
__launch_bounds__(256)
__global__ void agg1_gemm2_kernel(const float* __restrict__ hs, const int* __restrict__ csr,
                                  const int* __restrict__ offs, const float* __restrict__ dinv,
                                  const float* __restrict__ b1, const float* __restrict__ W2,
                                  float* __restrict__ hs2, int N) {
    __shared__ float W2s[FH * FO];       // 4 KB
    __shared__ float h1s[16][68];        // 68-float row stride (16B-aligned, non-pow2)
    const float4* hs4 = (const float4*)hs;
    int tid = threadIdx.x;
    for (int i = tid; i < FH * FO; i += 256) W2s[i] = W2[i];
    int g = tid >> 4, l = tid & 15;
    int n = blockIdx.x * 16 + g;
    if (n < N) {
        float4 acc = hs4[(size_t)n * 16 + l];      // self loop (pre-scaled)
        int j = offs[n], end = offs[n + 1];
        for (; j + 1 < end; j += 2) {              // 2 gathers in flight
            int s0 = csr[j], s1 = csr[j + 1];
            float4 a = hs4[(size_t)s0 * 16 + l];
            float4 b = hs4[(size_t)s1 * 16 + l];
            acc.x += a.x + b.x; acc.y += a.y + b.y;
            acc.z += a.z + b.z; acc.w += a.w + b.w;
        }
        if (j < end) {
            float4 a = hs4[(size_t)csr[j] * 16 + l];
            acc.x += a.x; acc.y += a.y; acc.z += a.z; acc.w += a.w;
        }
        float di = dinv[n];
        float4 bb = ((const float4*)b1)[l];
        float4 h;
        h.x = fmaxf(fmaf(di, acc.x, bb.x), 0.f);
        h.y = fmaxf(fmaf(di, acc.y, bb.y), 0.f);
        h.z = fmaxf(fmaf(di, acc.z, bb.z), 0.f);
        h.w = fmaxf(fmaf(di, acc.w, bb.w), 0.f);
        *((float4*)&h1s[g][l * 4]) = h;
    }
    __syncthreads();
    int r = tid >> 4, o = tid & 15;     // 16 rows x 16 out-cols
    int n2 = blockIdx.x * 16 + r;
    if (n2 < N) {
        float acc = 0.f;
        #pragma unroll
        for (int jj = 0; jj < FH; ++jj)
            acc = fmaf(h1s[r][jj], W2s[jj * FO + o], acc);
        hs2[(size_t)n2 * FO + o] = acc * dinv[n2];
    }
}

// ---------------------------------------------------------------------------
// Kernel: layer-2 PULL aggregation fused with bias + log_softmax.
// 16 nodes/block; 16 lanes per node, lane owns one of 16 classes.
// ---------------------------------------------------------------------------
__launch_bounds__(256)
__global__ void agg2_softmax_kernel(const float* __restrict__ hs2, const int* __restrict__ csr,
                                    const int* __restrict__ offs, const float* __restrict__ dinv,
                                    const float* __restrict__ b2, float* __restrict__ out, int N) {
    int tid = threadIdx.x;
    int g = tid >> 4, o = tid & 15;
    int n = blockIdx.x * 16 + g;
    float v = 0.f;
    if (n < N) {
        float acc = hs2[(size_t)n * 16 + o];       // self loop (pre-scaled)
        int j = offs[n], end = offs[n + 1];
        for (; j + 1 < end; j += 2) {
            int s0 = csr[j], s1 = csr[j + 1];
            acc += hs2[(size_t)s0 * 16 + o] + hs2[(size_t)s1 * 16 + o];
        }
        if (j < end) acc += hs2[(size_t)csr[j] * 16 + o];
        v = fmaf(dinv[n], acc, b2[o]);
    }
    float m = v;
    #pragma unroll
    for (int s = 8; s >= 1; s >>= 1) m = fmaxf(m, __shfl_xor(m, s, 64));
    float ex = __expf(v - m);
    float sum = ex;
    #pragma unroll
    for (int s = 8; s >= 1; s >>= 1) sum += __shfl_xor(sum, s, 64);
    if (n < N) out[(size_t)n * FO + o] = v - m - __logf(sum);
}

// ---------------------------------------------------------------------------
extern "C" void kernel_launch(void* const* d_in, const int* in_sizes, int n_in,
                              void* d_out, int out_size, void* d_ws, size_t ws_size,
                              hipStream_t stream) {
    const float* x  = (const float*)d_in[0];
    const int*   ei = (const int*)d_in[1];     // int32
    const float* W1 = (const float*)d_in[2];
    const float* b1 = (const float*)d_in[3];
    const float* W2 = (const float*)d_in[4];
    const float* b2 = (const float*)d_in[5];
    float* out = (float*)d_out;

    const int N = in_sizes[0] / FIN;
    const int E = in_sizes[1] / 2;
    const int NCHUNK = (E + EPB - 1) / EPB;         // binning/hist blocks
    const int NB4    = (N + BW - 1) / BW;           // buckets actually used

    char* ws = (char*)d_ws;
    size_t off = 0;
    auto alloc = [&](size_t bytes) -> void* {
        off = (off + 255) & ~(size_t)255;
        void* p = ws + off;
        off += bytes;
        return p;
    };
    float* dinv  = (float*)alloc((size_t)N * 4);            //  0.4 MB
    float* hs    = (float*)alloc((size_t)N * FH * 4);       // 25.6 MB
    float* hs2   = (float*)alloc((size_t)N * FO * 4);       //  6.4 MB
    int*   offs  = (int*)  alloc((size_t)(N + 1) * 4);      //  0.4 MB
    int*   bcnt  = (int*)  alloc(NBUCK * 4);
    int*   bbase = (int*)  alloc((NBUCK + 1) * 4);
    int*   gcur  = (int*)  alloc(NBUCK * 4);
    // ebuf + csr (2*E ints = 12.8 MB): in ws if it fits, else alias the x
    // input buffer (25.6 MB, dead after gemm1 which runs first; harness
    // restores d_in before every launch; ws_size constant -> capture-stable).
    unsigned* ebuf;
    int*      csr;
    if (ws_size >= off + 512 + (size_t)E * 8) {
        ebuf = (unsigned*)alloc((size_t)E * 4);
        csr  = (int*)     alloc((size_t)E * 4);
    } else {
        ebuf = (unsigned*)x;
        csr  = (int*)x + E;
    }

    hipMemsetAsync(bcnt, 0, NBUCK * 4, stream);

    gemm1_kernel<<<(N + 15) / 16, 256, 0, stream>>>(x, W1, hs, N);       // reads x (last use)
    hist_kernel<<<NCHUNK, 256, 0, stream>>>(ei, E, bcnt);
    bucket_scan_kernel<<<1, 1024, 0, stream>>>(bcnt, bbase, gcur, offs, N, E);
    binning_kernel<<<NCHUNK, 256, 0, stream>>>(ei, E, gcur, ebuf);       // may write x
    bucket_csr_kernel<<<NB4, 256, 0, stream>>>(ebuf, bbase, csr, offs, dinv, hs, N);
    agg1_gemm2_kernel<<<(N + 15) / 16, 256, 0, stream>>>(hs, csr, offs, dinv, b1, W2, hs2, N);
    agg2_softmax_kernel<<<(N + 15) / 16, 256, 0, stream>>>(hs2, csr, offs, dinv, b2, out, N);
}

// Round 6
// 266.180 us; speedup vs baseline: 7.1804x; 1.1182x over previous
//
#include <hip/hip_runtime.h>

// Feature dims fixed by the problem
constexpr int FIN = 64;   // input features
constexpr int FH  = 64;   // hidden
constexpr int FO  = 16;   // output

// edge_index arrives as int32 (harness integer convention), flat [2][E]:
// src = ei[e], dst = ei[e + E].

// Bucket sort parameters: bucket = dst >> 7 (128 nodes per bucket).
constexpr int BSH   = 7;
constexpr int BW    = 1 << BSH;    // 128 nodes / bucket
constexpr int NBUCK = 1024;        // covers N up to 131072
constexpr int EPB   = 16384;       // edges per binning block

// bf16 helpers (manual RNE; exact expand)
__device__ inline unsigned short f2bf(float f) {
    unsigned u = __float_as_uint(f);
    return (unsigned short)((u + 0x7FFFu + ((u >> 16) & 1u)) >> 16);
}
__device__ inline float bf2f(unsigned short h) {
    return __uint_as_float((unsigned)h << 16);
}
__device__ inline float4 bf4_to_f4(ushort4 u) {
    float4 f;
    f.x = bf2f(u.x); f.y = bf2f(u.y); f.z = bf2f(u.z); f.w = bf2f(u.w);
    return f;
}

// ---------------------------------------------------------------------------
// Fused kernel: blocks [0,G1) do hs_bf16 = bf16(x @ W1) (unscaled);
// blocks [G1, G1+NCHUNK) do the dst-bucket histogram. Per-block branch only.
// ---------------------------------------------------------------------------
__launch_bounds__(256)
__global__ void gemm1_hist_kernel(const float* __restrict__ x, const float* __restrict__ W1,
                                  unsigned short* __restrict__ hsb,
                                  const int* __restrict__ ei, int E,
                                  int* __restrict__ bcnt, int N, int G1) {
    __shared__ float smem[FIN * FH + 4 * FIN];   // 17 KB (gemm) >= 4 KB (hist ints)
    int tid = threadIdx.x;
    if ((int)blockIdx.x >= G1) {
        int* lh = (int*)smem;
        for (int i = tid; i < NBUCK; i += 256) lh[i] = 0;
        __syncthreads();
        int base = ((int)blockIdx.x - G1) * EPB;
        int lim  = min(E, base + EPB);
        for (int e = base + tid; e < lim; e += 256)
            atomicAdd(&lh[ei[E + e] >> BSH], 1);
        __syncthreads();
        for (int b = tid; b < NBUCK; b += 256) {
            int c = lh[b];
            if (c > 0) atomicAdd(&bcnt[b], c);
        }
        return;
    }
    float* Ws = smem;                 // [FIN*FH]
    float* xs = smem + FIN * FH;      // [4][FIN]
    for (int i = tid; i < FIN * FH; i += 256) Ws[i] = W1[i];
    int col = tid & 63;
    int rs  = tid >> 6;
    int rowBase = blockIdx.x * 16;
    for (int rr = 0; rr < 16; rr += 4) {
        int row = rowBase + rr + rs;
        __syncthreads();
        xs[rs * FIN + col] = (row < N) ? x[(size_t)row * FIN + col] : 0.f;
        __syncthreads();
        float acc = 0.f;
        #pragma unroll
        for (int k = 0; k < FIN; ++k)
            acc = fmaf(xs[rs * FIN + k], Ws[k * FH + col], acc);
        if (row < N) hsb[(size_t)row * FH + col] = f2bf(acc);
    }
}

// ---------------------------------------------------------------------------
// Kernel: exclusive scan of bucket counts -> bbase[NBUCK+1], init gcur.
// Single block of 1024 threads. Also writes offs[N] = E.
// ---------------------------------------------------------------------------
__launch_bounds__(1024)
__global__ void bucket_scan_kernel(const int* __restrict__ bcnt, int* __restrict__ bbase,
                                   int* __restrict__ gcur, int* __restrict__ offs,
                                   int N, int E) {
    __shared__ int s[NBUCK];
    int t = threadIdx.x;
    int v = bcnt[t];
    s[t] = v;
    __syncthreads();
    for (int d = 1; d < NBUCK; d <<= 1) {
        int u = (t >= d) ? s[t - d] : 0;
        __syncthreads();
        s[t] += u;
        __syncthreads();
    }
    int ex = s[t] - v;
    bbase[t] = ex;
    gcur[t]  = ex;
    if (t == NBUCK - 1) {
        bbase[NBUCK] = s[t];   // == E
        offs[N] = E;
    }
}

// ---------------------------------------------------------------------------
// Kernel: binning. Each block reserves contiguous per-bucket runs, then writes
// each edge once as packed word src | (dst & 127) << 17 (N < 2^17).
// ---------------------------------------------------------------------------
__launch_bounds__(256)
__global__ void binning_kernel(const int* __restrict__ ei, int E,
                               int* __restrict__ gcur, unsigned* __restrict__ ebuf) {
    __shared__ int lh[NBUCK];
    int t = threadIdx.x;
    for (int i = t; i < NBUCK; i += 256) lh[i] = 0;
    __syncthreads();
    int base = blockIdx.x * EPB;
    int lim  = min(E, base + EPB);
    for (int e = base + t; e < lim; e += 256)
        atomicAdd(&lh[ei[E + e] >> BSH], 1);
    __syncthreads();
    for (int b = t; b < NBUCK; b += 256) {
        int c = lh[b];
        lh[b] = (c > 0) ? atomicAdd(&gcur[b], c) : 0;   // run base -> running cursor
    }
    __syncthreads();
    for (int e = base + t; e < lim; e += 256) {
        int d = ei[E + e];
        int srcv = ei[e];
        int pos = atomicAdd(&lh[d >> BSH], 1);
        ebuf[pos] = (unsigned)srcv | ((unsigned)(d & (BW - 1)) << 17);
    }
}

// ---------------------------------------------------------------------------
// Kernel: per-bucket CSR build + dinv + offs. One block per bucket; all csr
// stores land in the block's own contiguous region (single-owner lines).
// ---------------------------------------------------------------------------
__launch_bounds__(256)
__global__ void bucket_csr_kernel(const unsigned* __restrict__ ebuf,
                                  const int* __restrict__ bbase,
                                  int* __restrict__ csr, int* __restrict__ offs,
                                  float* __restrict__ dinv, int N) {
    __shared__ int cnt[BW], sc[BW], cur[BW];
    int t = threadIdx.x;
    int b = blockIdx.x;
    if (t < BW) cnt[t] = 0;
    __syncthreads();
    int beg = bbase[b], end = bbase[b + 1];
    for (int i = beg + t; i < end; i += 256)
        atomicAdd(&cnt[ebuf[i] >> 17], 1);
    __syncthreads();
    if (t < BW) sc[t] = cnt[t];
    __syncthreads();
    for (int d = 1; d < BW; d <<= 1) {
        int u = (t < BW && t >= d) ? sc[t - d] : 0;
        __syncthreads();
        if (t < BW) sc[t] += u;
        __syncthreads();
    }
    int nodeBase = b << BSH;
    if (t < BW) {
        int node = nodeBase + t;
        int ex = beg + sc[t] - cnt[t];
        cur[t] = ex;
        if (node < N) {
            offs[node] = ex;
            dinv[node] = rsqrtf((float)(cnt[t] + 1));
        }
    }
    __syncthreads();
    for (int i = beg + t; i < end; i += 256) {
        unsigned w = ebuf[i];
        int pos = atomicAdd(&cur[w >> 17], 1);
        csr[pos] = (int)(w & 0x1FFFF);
    }
}

// ---------------------------------------------------------------------------
// Kernel: layer-1 PULL aggregation (bf16 gathers, per-src dinv scale in-reg)
// fused with finalize1 + GEMM2; writes hs2 pre-scaled as bf16.
// 16 nodes/block; 16 lanes per node, lane owns one ushort4 chunk (4 feats).
// ---------------------------------------------------------------------------
__launch_bounds__(256)
__global__ void agg1_gemm2_kernel(const unsigned short* __restrict__ hsb,
                                  const int* __restrict__ csr,
                                  const int* __restrict__ offs, const float* __restrict__ dinv,
                                  const float* __restrict__ b1, const float* __restrict__ W2,
                                  unsigned short* __restrict__ hs2b, int N) {
    __shared__ float W2s[FH * FO];       // 4 KB
    __shared__ float h1s[16][68];        // 68-float row stride (16B-aligned, non-pow2)
    const ushort4* hs4 = (const ushort4*)hsb;   // 16 ushort4 per row
    int tid = threadIdx.x;
    for (int i = tid; i < FH * FO; i += 256) W2s[i] = W2[i];
    int g = tid >> 4, l = tid & 15;
    int n = blockIdx.x * 16 + g;
    if (n < N) {
        float di_n = dinv[n];
        float4 self = bf4_to_f4(hs4[(size_t)n * 16 + l]);
        float4 acc;
        acc.x = self.x * di_n; acc.y = self.y * di_n;
        acc.z = self.z * di_n; acc.w = self.w * di_n;
        int j = offs[n], end = offs[n + 1];
        for (; j + 1 < end; j += 2) {              // 2 gathers in flight
            int s0 = csr[j], s1 = csr[j + 1];
            float d0 = dinv[s0], d1 = dinv[s1];
            float4 a = bf4_to_f4(hs4[(size_t)s0 * 16 + l]);
            float4 b = bf4_to_f4(hs4[(size_t)s1 * 16 + l]);
            acc.x = fmaf(a.x, d0, fmaf(b.x, d1, acc.x));
            acc.y = fmaf(a.y, d0, fmaf(b.y, d1, acc.y));
            acc.z = fmaf(a.z, d0, fmaf(b.z, d1, acc.z));
            acc.w = fmaf(a.w, d0, fmaf(b.w, d1, acc.w));
        }
        if (j < end) {
            int s0 = csr[j];
            float d0 = dinv[s0];
            float4 a = bf4_to_f4(hs4[(size_t)s0 * 16 + l]);
            acc.x = fmaf(a.x, d0, acc.x); acc.y = fmaf(a.y, d0, acc.y);
            acc.z = fmaf(a.z, d0, acc.z); acc.w = fmaf(a.w, d0, acc.w);
        }
        float4 bb = ((const float4*)b1)[l];
        float4 h;
        h.x = fmaxf(fmaf(di_n, acc.x, bb.x), 0.f);
        h.y = fmaxf(fmaf(di_n, acc.y, bb.y), 0.f);
        h.z = fmaxf(fmaf(di_n, acc.z, bb.z), 0.f);
        h.w = fmaxf(fmaf(di_n, acc.w, bb.w), 0.f);
        *((float4*)&h1s[g][l * 4]) = h;
    }
    __syncthreads();
    int r = tid >> 4, o = tid & 15;     // 16 rows x 16 out-cols
    int n2 = blockIdx.x * 16 + r;
    if (n2 < N) {
        float acc = 0.f;
        #pragma unroll
        for (int jj = 0; jj < FH; ++jj)
            acc = fmaf(h1s[r][jj], W2s[jj * FO + o], acc);
        hs2b[(size_t)n2 * FO + o] = f2bf(acc * dinv[n2]);   // pre-scaled bf16
    }
}

// ---------------------------------------------------------------------------
// Kernel: layer-2 PULL aggregation fused with bias + log_softmax.
// hs2b table is 3.2 MB -> fits per-XCD L2; gathers are 2B/lane.
// ---------------------------------------------------------------------------
__launch_bounds__(256)
__global__ void agg2_softmax_kernel(const unsigned short* __restrict__ hs2b,
                                    const int* __restrict__ csr,
                                    const int* __restrict__ offs, const float* __restrict__ dinv,
                                    const float* __restrict__ b2, float* __restrict__ out, int N) {
    int tid = threadIdx.x;
    int g = tid >> 4, o = tid & 15;
    int n = blockIdx.x * 16 + g;
    float v = 0.f;
    if (n < N) {
        float acc = bf2f(hs2b[(size_t)n * 16 + o]);    // self loop (pre-scaled)
        int j = offs[n], end = offs[n + 1];
        for (; j + 1 < end; j += 2) {
            int s0 = csr[j], s1 = csr[j + 1];
            acc += bf2f(hs2b[(size_t)s0 * 16 + o]) + bf2f(hs2b[(size_t)s1 * 16 + o]);
        }
        if (j < end) acc += bf2f(hs2b[(size_t)csr[j] * 16 + o]);
        v = fmaf(dinv[n], acc, b2[o]);
    }
    float m = v;
    #pragma unroll
    for (int s = 8; s >= 1; s >>= 1) m = fmaxf(m, __shfl_xor(m, s, 64));
    float ex = __expf(v - m);
    float sum = ex;
    #pragma unroll
    for (int s = 8; s >= 1; s >>= 1) sum += __shfl_xor(sum, s, 64);
    if (n < N) out[(size_t)n * FO + o] = v - m - __logf(sum);
}

// ---------------------------------------------------------------------------
extern "C" void kernel_launch(void* const* d_in, const int* in_sizes, int n_in,
                              void* d_out, int out_size, void* d_ws, size_t ws_size,
                              hipStream_t stream) {
    const float* x  = (const float*)d_in[0];
    const int*   ei = (const int*)d_in[1];     // int32
    const float* W1 = (const float*)d_in[2];
    const float* b1 = (const float*)d_in[3];
    const float* W2 = (const float*)d_in[4];
    const float* b2 = (const float*)d_in[5];
    float* out = (float*)d_out;

    const int N = in_sizes[0] / FIN;
    const int E = in_sizes[1] / 2;
    const int NCHUNK = (E + EPB - 1) / EPB;         // hist/binning blocks
    const int NB4    = (N + BW - 1) / BW;           // buckets actually used
    const int G1     = (N + 15) / 16;               // gemm blocks

    char* ws = (char*)d_ws;
    size_t off = 0;
    auto alloc = [&](size_t bytes) -> void* {
        off = (off + 255) & ~(size_t)255;
        void* p = ws + off;
        off += bytes;
        return p;
    };
    float*          dinv  = (float*)alloc((size_t)N * 4);               //  0.4 MB
    unsigned short* hsb   = (unsigned short*)alloc((size_t)N * FH * 2); // 12.8 MB
    unsigned short* hs2b  = (unsigned short*)alloc((size_t)N * FO * 2); //  3.2 MB
    int*            offs  = (int*)alloc((size_t)(N + 1) * 4);           //  0.4 MB
    int*            bcnt  = (int*)alloc(NBUCK * 4);
    int*            bbase = (int*)alloc((NBUCK + 1) * 4);
    int*            gcur  = (int*)alloc(NBUCK * 4);
    // ebuf + csr (2*E ints = 12.8 MB): in ws if it fits, else alias the x
    // input buffer (25.6 MB, dead after gemm1_hist which runs first; harness
    // restores d_in before every launch; ws_size constant -> capture-stable).
    unsigned* ebuf;
    int*      csr;
    if (ws_size >= off + 512 + (size_t)E * 8) {
        ebuf = (unsigned*)alloc((size_t)E * 4);
        csr  = (int*)     alloc((size_t)E * 4);
    } else {
        ebuf = (unsigned*)x;
        csr  = (int*)x + E;
    }

    hipMemsetAsync(bcnt, 0, NBUCK * 4, stream);

    gemm1_hist_kernel<<<G1 + NCHUNK, 256, 0, stream>>>(x, W1, hsb, ei, E, bcnt, N, G1); // reads x
    bucket_scan_kernel<<<1, NBUCK, 0, stream>>>(bcnt, bbase, gcur, offs, N, E);
    binning_kernel<<<NCHUNK, 256, 0, stream>>>(ei, E, gcur, ebuf);       // may write x
    bucket_csr_kernel<<<NB4, 256, 0, stream>>>(ebuf, bbase, csr, offs, dinv, N);
    agg1_gemm2_kernel<<<G1, 256, 0, stream>>>(hsb, csr, offs, dinv, b1, W2, hs2b, N);
    agg2_softmax_kernel<<<G1, 256, 0, stream>>>(hs2b, csr, offs, dinv, b2, out, N);
}

// Round 7
// 242.261 us; speedup vs baseline: 7.8893x; 1.0987x over previous
//
#include <hip/hip_runtime.h>

// Feature dims fixed by the problem
constexpr int FIN = 64;   // input features
constexpr int FH  = 64;   // hidden
constexpr int FO  = 16;   // output

// edge_index arrives as int32 (harness integer convention), flat [2][E]:
// src = ei[e], dst = ei[e + E].

// Bucket sort parameters: bucket = dst >> 7 (128 nodes per bucket).
constexpr int BSH   = 7;
constexpr int BW    = 1 << BSH;    // 128 nodes / bucket
constexpr int NBUCK = 1024;        // covers N up to 131072
constexpr int EPB   = 16384;       // edges per binning block

constexpr int XT_STRIDE = 68;      // xsT row stride (floats): 16B-aligned, non-pow2

// bf16 helpers (manual RNE; exact expand)
__device__ inline unsigned short f2bf(float f) {
    unsigned u = __float_as_uint(f);
    return (unsigned short)((u + 0x7FFFu + ((u >> 16) & 1u)) >> 16);
}
__device__ inline float bf2f(unsigned short h) {
    return __uint_as_float((unsigned)h << 16);
}
__device__ inline float4 bf4_to_f4(ushort4 u) {
    float4 f;
    f.x = bf2f(u.x); f.y = bf2f(u.y); f.z = bf2f(u.z); f.w = bf2f(u.w);
    return f;
}

// ---------------------------------------------------------------------------
// Fused kernel: blocks [0,G1T) do hs_bf16 = bf16(x @ W1) (unscaled) with a
// 4x4 register-blocked tile per thread (64 rows per block); blocks
// [G1T, G1T+NCHUNK) do the dst-bucket histogram. Per-block branch only.
// ---------------------------------------------------------------------------
__launch_bounds__(256)
__global__ void gemm1_hist_kernel(const float* __restrict__ x, const float* __restrict__ W1,
                                  unsigned short* __restrict__ hsb,
                                  const int* __restrict__ ei, int E,
                                  int* __restrict__ bcnt, int N, int G1T) {
    __shared__ float smem[FIN * FH + 64 * XT_STRIDE];   // 16 KB Ws + 17 KB xsT
    int tid = threadIdx.x;
    if ((int)blockIdx.x >= G1T) {
        // ---- histogram phase ----
        int* lh = (int*)smem;
        for (int i = tid; i < NBUCK; i += 256) lh[i] = 0;
        __syncthreads();
        int base = ((int)blockIdx.x - G1T) * EPB;
        int lim  = min(E, base + EPB);
        for (int e = base + tid; e < lim; e += 256)
            atomicAdd(&lh[ei[E + e] >> BSH], 1);
        __syncthreads();
        for (int b = tid; b < NBUCK; b += 256) {
            int c = lh[b];
            if (c > 0) atomicAdd(&bcnt[b], c);
        }
        return;
    }
    // ---- GEMM phase: 64-row tile, 4x4 register block per thread ----
    float* Ws  = smem;                 // [64][64] row-major (k, col)
    float* xsT = smem + FIN * FH;      // [64][XT_STRIDE] transposed x tile (k, row)
    // Stage W1 (4096 floats = 1024 float4)
    {
        const float4* W14 = (const float4*)W1;
        float4* Ws4 = (float4*)Ws;
        for (int i = tid; i < 1024; i += 256) Ws4[i] = W14[i];
    }
    // Stage x tile transposed: row-major float4 loads, scattered LDS writes
    // (write bank = (c*16 + row) % 32 pattern -> 2-way max, free).
    int rowBase = blockIdx.x * 64;
    const float4* x4 = (const float4*)x;
    #pragma unroll
    for (int p = 0; p < 4; ++p) {
        int f   = tid + p * 256;      // 0..1023
        int row = f >> 4;             // 0..63
        int c4  = f & 15;             // float4 index within row
        int grow = rowBase + row;
        float4 v = (grow < N) ? x4[(size_t)grow * 16 + c4]
                              : make_float4(0.f, 0.f, 0.f, 0.f);
        xsT[(c4 * 4 + 0) * XT_STRIDE + row] = v.x;
        xsT[(c4 * 4 + 1) * XT_STRIDE + row] = v.y;
        xsT[(c4 * 4 + 2) * XT_STRIDE + row] = v.z;
        xsT[(c4 * 4 + 3) * XT_STRIDE + row] = v.w;
    }
    __syncthreads();
    int cg = tid & 15;        // col group: cols cg*4..+3
    int rg = tid >> 4;        // row group: rows rg*4..+3 (0..15)
    float4 a0 = {0,0,0,0}, a1 = {0,0,0,0}, a2 = {0,0,0,0}, a3 = {0,0,0,0};
    #pragma unroll 8
    for (int k = 0; k < FIN; ++k) {
        float4 wv = *(const float4*)&Ws[k * FH + cg * 4];
        float4 xv = *(const float4*)&xsT[k * XT_STRIDE + rg * 4];
        a0.x = fmaf(xv.x, wv.x, a0.x); a0.y = fmaf(xv.x, wv.y, a0.y);
        a0.z = fmaf(xv.x, wv.z, a0.z); a0.w = fmaf(xv.x, wv.w, a0.w);
        a1.x = fmaf(xv.y, wv.x, a1.x); a1.y = fmaf(xv.y, wv.y, a1.y);
        a1.z = fmaf(xv.y, wv.z, a1.z); a1.w = fmaf(xv.y, wv.w, a1.w);
        a2.x = fmaf(xv.z, wv.x, a2.x); a2.y = fmaf(xv.z, wv.y, a2.y);
        a2.z = fmaf(xv.z, wv.z, a2.z); a2.w = fmaf(xv.z, wv.w, a2.w);
        a3.x = fmaf(xv.w, wv.x, a3.x); a3.y = fmaf(xv.w, wv.y, a3.y);
        a3.z = fmaf(xv.w, wv.z, a3.z); a3.w = fmaf(xv.w, wv.w, a3.w);
    }
    ushort4* hsb4 = (ushort4*)hsb;
    {
        int grow = rowBase + rg * 4 + 0;
        if (grow < N) hsb4[(size_t)grow * 16 + cg] =
            make_ushort4(f2bf(a0.x), f2bf(a0.y), f2bf(a0.z), f2bf(a0.w));
        grow = rowBase + rg * 4 + 1;
        if (grow < N) hsb4[(size_t)grow * 16 + cg] =
            make_ushort4(f2bf(a1.x), f2bf(a1.y), f2bf(a1.z), f2bf(a1.w));
        grow = rowBase + rg * 4 + 2;
        if (grow < N) hsb4[(size_t)grow * 16 + cg] =
            make_ushort4(f2bf(a2.x), f2bf(a2.y), f2bf(a2.z), f2bf(a2.w));
        grow = rowBase + rg * 4 + 3;
        if (grow < N) hsb4[(size_t)grow * 16 + cg] =
            make_ushort4(f2bf(a3.x), f2bf(a3.y), f2bf(a3.z), f2bf(a3.w));
    }
}

// ---------------------------------------------------------------------------
// Kernel: exclusive scan of bucket counts -> bbase[NBUCK+1], init gcur.
// Single block of 1024 threads. Also writes offs[N] = E.
// ---------------------------------------------------------------------------
__launch_bounds__(1024)
__global__ void bucket_scan_kernel(const int* __restrict__ bcnt, int* __restrict__ bbase,
                                   int* __restrict__ gcur, int* __restrict__ offs,
                                   int N, int E) {
    __shared__ int s[NBUCK];
    int t = threadIdx.x;
    int v = bcnt[t];
    s[t] = v;
    __syncthreads();
    for (int d = 1; d < NBUCK; d <<= 1) {
        int u = (t >= d) ? s[t - d] : 0;
        __syncthreads();
        s[t] += u;
        __syncthreads();
    }
    int ex = s[t] - v;
    bbase[t] = ex;
    gcur[t]  = ex;
    if (t == NBUCK - 1) {
        bbase[NBUCK] = s[t];   // == E
        offs[N] = E;
    }
}

// ---------------------------------------------------------------------------
// Kernel: binning. Each block reserves contiguous per-bucket runs, then writes
// each edge once as packed word src | (dst & 127) << 17 (N < 2^17).
// ---------------------------------------------------------------------------
__launch_bounds__(256)
__global__ void binning_kernel(const int* __restrict__ ei, int E,
                               int* __restrict__ gcur, unsigned* __restrict__ ebuf) {
    __shared__ int lh[NBUCK];
    int t = threadIdx.x;
    for (int i = t; i < NBUCK; i += 256) lh[i] = 0;
    __syncthreads();
    int base = blockIdx.x * EPB;
    int lim  = min(E, base + EPB);
    for (int e = base + t; e < lim; e += 256)
        atomicAdd(&lh[ei[E + e] >> BSH], 1);
    __syncthreads();
    for (int b = t; b < NBUCK; b += 256) {
        int c = lh[b];
        lh[b] = (c > 0) ? atomicAdd(&gcur[b], c) : 0;   // run base -> running cursor
    }
    __syncthreads();
    for (int e = base + t; e < lim; e += 256) {
        int d = ei[E + e];
        int srcv = ei[e];
        int pos = atomicAdd(&lh[d >> BSH], 1);
        ebuf[pos] = (unsigned)srcv | ((unsigned)(d & (BW - 1)) << 17);
    }
}

// ---------------------------------------------------------------------------
// Kernel: per-bucket CSR build + dinv + offs. One block per bucket; all csr
// stores land in the block's own contiguous region (single-owner lines).
// ---------------------------------------------------------------------------
__launch_bounds__(256)
__global__ void bucket_csr_kernel(const unsigned* __restrict__ ebuf,
                                  const int* __restrict__ bbase,
                                  int* __restrict__ csr, int* __restrict__ offs,
                                  float* __restrict__ dinv, int N) {
    __shared__ int cnt[BW], sc[BW], cur[BW];
    int t = threadIdx.x;
    int b = blockIdx.x;
    if (t < BW) cnt[t] = 0;
    __syncthreads();
    int beg = bbase[b], end = bbase[b + 1];
    for (int i = beg + t; i < end; i += 256)
        atomicAdd(&cnt[ebuf[i] >> 17], 1);
    __syncthreads();
    if (t < BW) sc[t] = cnt[t];
    __syncthreads();
    for (int d = 1; d < BW; d <<= 1) {
        int u = (t < BW && t >= d) ? sc[t - d] : 0;
        __syncthreads();
        if (t < BW) sc[t] += u;
        __syncthreads();
    }
    int nodeBase = b << BSH;
    if (t < BW) {
        int node = nodeBase + t;
        int ex = beg + sc[t] - cnt[t];
        cur[t] = ex;
        if (node < N) {
            offs[node] = ex;
            dinv[node] = rsqrtf((float)(cnt[t] + 1));
        }
    }
    __syncthreads();
    for (int i = beg + t; i < end; i += 256) {
        unsigned w = ebuf[i];
        int pos = atomicAdd(&cur[w >> 17], 1);
        csr[pos] = (int)(w & 0x1FFFF);
    }
}

// ---------------------------------------------------------------------------
// Kernel: layer-1 PULL aggregation (bf16 gathers, per-src dinv scale in-reg)
// fused with finalize1 + GEMM2; writes hs2 pre-scaled as bf16.
// 16 nodes/block; 16 lanes per node, lane owns one ushort4 chunk (4 feats).
// ---------------------------------------------------------------------------
__launch_bounds__(256)
__global__ void agg1_gemm2_kernel(const unsigned short* __restrict__ hsb,
                                  const int* __restrict__ csr,
                                  const int* __restrict__ offs, const float* __restrict__ dinv,
                                  const float* __restrict__ b1, const float* __restrict__ W2,
                                  unsigned short* __restrict__ hs2b, int N) {
    __shared__ float W2s[FH * FO];       // 4 KB
    __shared__ float h1s[16][68];        // 68-float row stride (16B-aligned, non-pow2)
    const ushort4* hs4 = (const ushort4*)hsb;   // 16 ushort4 per row
    int tid = threadIdx.x;
    for (int i = tid; i < FH * FO; i += 256) W2s[i] = W2[i];
    int g = tid >> 4, l = tid & 15;
    int n = blockIdx.x * 16 + g;
    if (n < N) {
        float di_n = dinv[n];
        float4 self = bf4_to_f4(hs4[(size_t)n * 16 + l]);
        float4 acc;
        acc.x = self.x * di_n; acc.y = self.y * di_n;
        acc.z = self.z * di_n; acc.w = self.w * di_n;
        int j = offs[n], end = offs[n + 1];
        for (; j + 1 < end; j += 2) {              // 2 gathers in flight
            int s0 = csr[j], s1 = csr[j + 1];
            float d0 = dinv[s0], d1 = dinv[s1];
            float4 a = bf4_to_f4(hs4[(size_t)s0 * 16 + l]);
            float4 b = bf4_to_f4(hs4[(size_t)s1 * 16 + l]);
            acc.x = fmaf(a.x, d0, fmaf(b.x, d1, acc.x));
            acc.y = fmaf(a.y, d0, fmaf(b.y, d1, acc.y));
            acc.z = fmaf(a.z, d0, fmaf(b.z, d1, acc.z));
            acc.w = fmaf(a.w, d0, fmaf(b.w, d1, acc.w));
        }
        if (j < end) {
            int s0 = csr[j];
            float d0 = dinv[s0];
            float4 a = bf4_to_f4(hs4[(size_t)s0 * 16 + l]);
            acc.x = fmaf(a.x, d0, acc.x); acc.y = fmaf(a.y, d0, acc.y);
            acc.z = fmaf(a.z, d0, acc.z); acc.w = fmaf(a.w, d0, acc.w);
        }
        float4 bb = ((const float4*)b1)[l];
        float4 h;
        h.x = fmaxf(fmaf(di_n, acc.x, bb.x), 0.f);
        h.y = fmaxf(fmaf(di_n, acc.y, bb.y), 0.f);
        h.z = fmaxf(fmaf(di_n, acc.z, bb.z), 0.f);
        h.w = fmaxf(fmaf(di_n, acc.w, bb.w), 0.f);
        *((float4*)&h1s[g][l * 4]) = h;
    }
    __syncthreads();
    int r = tid >> 4, o = tid & 15;     // 16 rows x 16 out-cols
    int n2 = blockIdx.x * 16 + r;
    if (n2 < N) {
        float acc = 0.f;
        #pragma unroll
        for (int jj = 0; jj < FH; ++jj)
            acc = fmaf(h1s[r][jj], W2s[jj * FO + o], acc);
        hs2b[(size_t)n2 * FO + o] = f2bf(acc * dinv[n2]);   // pre-scaled bf16
    }
}

// ---------------------------------------------------------------------------
// Kernel: layer-2 PULL aggregation fused with bias + log_softmax.
// hs2b table is 3.2 MB -> fits per-XCD L2; gathers are 2B/lane.
// ---------------------------------------------------------------------------
__launch_bounds__(256)
__global__ void agg2_softmax_kernel(const unsigned short* __restrict__ hs2b,
                                    const int* __restrict__ csr,
                                    const int* __restrict__ offs, const float* __restrict__ dinv,
                                    const float* __restrict__ b2, float* __restrict__ out, int N) {
    int tid = threadIdx.x;
    int g = tid >> 4, o = tid & 15;
    int n = blockIdx.x * 16 + g;
    float v = 0.f;
    if (n < N) {
        float acc = bf2f(hs2b[(size_t)n * 16 + o]);    // self loop (pre-scaled)
        int j = offs[n], end = offs[n + 1];
        for (; j + 1 < end; j += 2) {
            int s0 = csr[j], s1 = csr[j + 1];
            acc += bf2f(hs2b[(size_t)s0 * 16 + o]) + bf2f(hs2b[(size_t)s1 * 16 + o]);
        }
        if (j < end) acc += bf2f(hs2b[(size_t)csr[j] * 16 + o]);
        v = fmaf(dinv[n], acc, b2[o]);
    }
    float m = v;
    #pragma unroll
    for (int s = 8; s >= 1; s >>= 1) m = fmaxf(m, __shfl_xor(m, s, 64));
    float ex = __expf(v - m);
    float sum = ex;
    #pragma unroll
    for (int s = 8; s >= 1; s >>= 1) sum += __shfl_xor(sum, s, 64);
    if (n < N) out[(size_t)n * FO + o] = v - m - __logf(sum);
}

// ---------------------------------------------------------------------------
extern "C" void kernel_launch(void* const* d_in, const int* in_sizes, int n_in,
                              void* d_out, int out_size, void* d_ws, size_t ws_size,
                              hipStream_t stream) {
    const float* x  = (const float*)d_in[0];
    const int*   ei = (const int*)d_in[1];     // int32
    const float* W1 = (const float*)d_in[2];
    const float* b1 = (const float*)d_in[3];
    const float* W2 = (const float*)d_in[4];
    const float* b2 = (const float*)d_in[5];
    float* out = (float*)d_out;

    const int N = in_sizes[0] / FIN;
    const int E = in_sizes[1] / 2;
    const int NCHUNK = (E + EPB - 1) / EPB;         // hist/binning blocks
    const int NB4    = (N + BW - 1) / BW;           // buckets actually used
    const int G1T    = (N + 63) / 64;               // gemm 64-row tiles
    const int GA     = (N + 15) / 16;               // agg blocks

    char* ws = (char*)d_ws;
    size_t off = 0;
    auto alloc = [&](size_t bytes) -> void* {
        off = (off + 255) & ~(size_t)255;
        void* p = ws + off;
        off += bytes;
        return p;
    };
    float*          dinv  = (float*)alloc((size_t)N * 4);               //  0.4 MB
    unsigned short* hsb   = (unsigned short*)alloc((size_t)N * FH * 2); // 12.8 MB
    unsigned short* hs2b  = (unsigned short*)alloc((size_t)N * FO * 2); //  3.2 MB
    int*            offs  = (int*)alloc((size_t)(N + 1) * 4);           //  0.4 MB
    int*            bcnt  = (int*)alloc(NBUCK * 4);
    int*            bbase = (int*)alloc((NBUCK + 1) * 4);
    int*            gcur  = (int*)alloc(NBUCK * 4);
    // ebuf + csr (2*E ints = 12.8 MB): in ws if it fits, else alias the x
    // input buffer (25.6 MB, dead after gemm1_hist which runs first; harness
    // restores d_in before every launch; ws_size constant -> capture-stable).
    unsigned* ebuf;
    int*      csr;
    if (ws_size >= off + 512 + (size_t)E * 8) {
        ebuf = (unsigned*)alloc((size_t)E * 4);
        csr  = (int*)     alloc((size_t)E * 4);
    } else {
        ebuf = (unsigned*)x;
        csr  = (int*)x + E;
    }

    hipMemsetAsync(bcnt, 0, NBUCK * 4, stream);

    gemm1_hist_kernel<<<G1T + NCHUNK, 256, 0, stream>>>(x, W1, hsb, ei, E, bcnt, N, G1T); // reads x
    bucket_scan_kernel<<<1, NBUCK, 0, stream>>>(bcnt, bbase, gcur, offs, N, E);
    binning_kernel<<<NCHUNK, 256, 0, stream>>>(ei, E, gcur, ebuf);       // may write x
    bucket_csr_kernel<<<NB4, 256, 0, stream>>>(ebuf, bbase, csr, offs, dinv, N);
    agg1_gemm2_kernel<<<GA, 256, 0, stream>>>(hsb, csr, offs, dinv, b1, W2, hs2b, N);
    agg2_softmax_kernel<<<GA, 256, 0, stream>>>(hs2b, csr, offs, dinv, b2, out, N);
}

// Round 8
// 213.696 us; speedup vs baseline: 8.9439x; 1.1337x over previous
//
#include <hip/hip_runtime.h>

// Feature dims fixed by the problem
constexpr int FIN = 64;   // input features
constexpr int FH  = 64;   // hidden
constexpr int FO  = 16;   // output

// edge_index arrives as int32 (harness integer convention), flat [2][E]:
// src = ei[e], dst = ei[e + E].

// Bucket sort parameters: bucket = dst >> 7 (128 nodes per bucket).
constexpr int BSH      = 7;
constexpr int BW       = 1 << BSH;  // 128 nodes / bucket
constexpr int NBUCK    = 1024;      // covers N up to 131072
constexpr int EPB_HIST = 16384;     // edges per hist block
constexpr int EPB_BIN  = 4096;      // edges per binning block (4x parallelism)

constexpr int XT_STRIDE = 68;       // xsT row stride (floats): 16B-aligned, non-pow2

// bf16 helpers (manual RNE; exact expand)
__device__ inline unsigned short f2bf(float f) {
    unsigned u = __float_as_uint(f);
    return (unsigned short)((u + 0x7FFFu + ((u >> 16) & 1u)) >> 16);
}
__device__ inline float bf2f(unsigned short h) {
    return __uint_as_float((unsigned)h << 16);
}
__device__ inline float4 bf4_to_f4(ushort4 u) {
    float4 f;
    f.x = bf2f(u.x); f.y = bf2f(u.y); f.z = bf2f(u.z); f.w = bf2f(u.w);
    return f;
}

// ---------------------------------------------------------------------------
// Kernel: dst-bucket histogram (standalone; 98 blocks, cheap).
// ---------------------------------------------------------------------------
__launch_bounds__(256)
__global__ void hist_kernel(const int* __restrict__ ei, int E, int* __restrict__ bcnt) {
    __shared__ int lh[NBUCK];
    int t = threadIdx.x;
    for (int i = t; i < NBUCK; i += 256) lh[i] = 0;
    __syncthreads();
    int base = blockIdx.x * EPB_HIST;
    int lim  = min(E, base + EPB_HIST);
    for (int e = base + t; e < lim; e += 256)
        atomicAdd(&lh[ei[E + e] >> BSH], 1);
    __syncthreads();
    for (int b = t; b < NBUCK; b += 256) {
        int c = lh[b];
        if (c > 0) atomicAdd(&bcnt[b], c);
    }
}

// ---------------------------------------------------------------------------
// Kernel: exclusive scan of bucket counts -> bbase[NBUCK+1], init gcur.
// Single block of 1024 threads. Also writes offs[N] = E.
// ---------------------------------------------------------------------------
__launch_bounds__(1024)
__global__ void bucket_scan_kernel(const int* __restrict__ bcnt, int* __restrict__ bbase,
                                   int* __restrict__ gcur, int* __restrict__ offs,
                                   int N, int E) {
    __shared__ int s[NBUCK];
    int t = threadIdx.x;
    int v = bcnt[t];
    s[t] = v;
    __syncthreads();
    for (int d = 1; d < NBUCK; d <<= 1) {
        int u = (t >= d) ? s[t - d] : 0;
        __syncthreads();
        s[t] += u;
        __syncthreads();
    }
    int ex = s[t] - v;
    bbase[t] = ex;
    gcur[t]  = ex;
    if (t == NBUCK - 1) {
        bbase[NBUCK] = s[t];   // == E
        offs[N] = E;
    }
}

// ---------------------------------------------------------------------------
// Binning device body: reserve contiguous per-bucket runs, write each edge
// once as packed word src | (dst & 127) << 17 (N < 2^17).
// ---------------------------------------------------------------------------
__device__ inline void binning_body(const int* __restrict__ ei, int E, int chunk,
                                    int* __restrict__ gcur, unsigned* __restrict__ ebuf,
                                    int* lh) {
    int t = threadIdx.x;
    for (int i = t; i < NBUCK; i += 256) lh[i] = 0;
    __syncthreads();
    int base = chunk * EPB_BIN;
    int lim  = min(E, base + EPB_BIN);
    for (int e = base + t; e < lim; e += 256)
        atomicAdd(&lh[ei[E + e] >> BSH], 1);
    __syncthreads();
    for (int b = t; b < NBUCK; b += 256) {
        int c = lh[b];
        lh[b] = (c > 0) ? atomicAdd(&gcur[b], c) : 0;   // run base -> running cursor
    }
    __syncthreads();
    for (int e = base + t; e < lim; e += 256) {
        int d = ei[E + e];
        int srcv = ei[e];
        int pos = atomicAdd(&lh[d >> BSH], 1);
        ebuf[pos] = (unsigned)srcv | ((unsigned)(d & (BW - 1)) << 17);
    }
}

__launch_bounds__(256)
__global__ void binning_kernel(const int* __restrict__ ei, int E,
                               int* __restrict__ gcur, unsigned* __restrict__ ebuf) {
    __shared__ int lh[NBUCK];
    binning_body(ei, E, blockIdx.x, gcur, ebuf, lh);
}

// ---------------------------------------------------------------------------
// Fused kernel: blocks [0,G1T) do hs_bf16 = bf16(x @ W1) (unscaled, 4x4
// register-blocked, 64 rows/block); blocks [G1T, G1T+nbin) do binning.
// The latency-bound binning blocks hide under the VALU-bound gemm blocks.
// Only launched with nbin>0 when ebuf does NOT alias x.
// ---------------------------------------------------------------------------
__launch_bounds__(256)
__global__ void gemm1_binning_kernel(const float* __restrict__ x, const float* __restrict__ W1,
                                     unsigned short* __restrict__ hsb,
                                     const int* __restrict__ ei, int E,
                                     int* __restrict__ gcur, unsigned* __restrict__ ebuf,
                                     int N, int G1T) {
    __shared__ float smem[FIN * FH + 64 * XT_STRIDE];   // 33 KB (gemm) >= 4 KB (binning)
    int tid = threadIdx.x;
    if ((int)blockIdx.x >= G1T) {
        binning_body(ei, E, (int)blockIdx.x - G1T, gcur, ebuf, (int*)smem);
        return;
    }
    // ---- GEMM phase: 64-row tile, 4x4 register block per thread ----
    float* Ws  = smem;                 // [64][64] row-major (k, col)
    float* xsT = smem + FIN * FH;      // [64][XT_STRIDE] transposed x tile (k, row)
    {
        const float4* W14 = (const float4*)W1;
        float4* Ws4 = (float4*)Ws;
        for (int i = tid; i < 1024; i += 256) Ws4[i] = W14[i];
    }
    int rowBase = blockIdx.x * 64;
    const float4* x4 = (const float4*)x;
    #pragma unroll
    for (int p = 0; p < 4; ++p) {
        int f   = tid + p * 256;      // 0..1023
        int row = f >> 4;             // 0..63
        int c4  = f & 15;             // float4 index within row
        int grow = rowBase + row;
        float4 v = (grow < N) ? x4[(size_t)grow * 16 + c4]
                              : make_float4(0.f, 0.f, 0.f, 0.f);
        xsT[(c4 * 4 + 0) * XT_STRIDE + row] = v.x;
        xsT[(c4 * 4 + 1) * XT_STRIDE + row] = v.y;
        xsT[(c4 * 4 + 2) * XT_STRIDE + row] = v.z;
        xsT[(c4 * 4 + 3) * XT_STRIDE + row] = v.w;
    }
    __syncthreads();
    int cg = tid & 15;        // col group: cols cg*4..+3
    int rg = tid >> 4;        // row group: rows rg*4..+3 (0..15)
    float4 a0 = {0,0,0,0}, a1 = {0,0,0,0}, a2 = {0,0,0,0}, a3 = {0,0,0,0};
    #pragma unroll 8
    for (int k = 0; k < FIN; ++k) {
        float4 wv = *(const float4*)&Ws[k * FH + cg * 4];
        float4 xv = *(const float4*)&xsT[k * XT_STRIDE + rg * 4];
        a0.x = fmaf(xv.x, wv.x, a0.x); a0.y = fmaf(xv.x, wv.y, a0.y);
        a0.z = fmaf(xv.x, wv.z, a0.z); a0.w = fmaf(xv.x, wv.w, a0.w);
        a1.x = fmaf(xv.y, wv.x, a1.x); a1.y = fmaf(xv.y, wv.y, a1.y);
        a1.z = fmaf(xv.y, wv.z, a1.z); a1.w = fmaf(xv.y, wv.w, a1.w);
        a2.x = fmaf(xv.z, wv.x, a2.x); a2.y = fmaf(xv.z, wv.y, a2.y);
        a2.z = fmaf(xv.z, wv.z, a2.z); a2.w = fmaf(xv.z, wv.w, a2.w);
        a3.x = fmaf(xv.w, wv.x, a3.x); a3.y = fmaf(xv.w, wv.y, a3.y);
        a3.z = fmaf(xv.w, wv.z, a3.z); a3.w = fmaf(xv.w, wv.w, a3.w);
    }
    ushort4* hsb4 = (ushort4*)hsb;
    {
        int grow = rowBase + rg * 4 + 0;
        if (grow < N) hsb4[(size_t)grow * 16 + cg] =
            make_ushort4(f2bf(a0.x), f2bf(a0.y), f2bf(a0.z), f2bf(a0.w));
        grow = rowBase + rg * 4 + 1;
        if (grow < N) hsb4[(size_t)grow * 16 + cg] =
            make_ushort4(f2bf(a1.x), f2bf(a1.y), f2bf(a1.z), f2bf(a1.w));
        grow = rowBase + rg * 4 + 2;
        if (grow < N) hsb4[(size_t)grow * 16 + cg] =
            make_ushort4(f2bf(a2.x), f2bf(a2.y), f2bf(a2.z), f2bf(a2.w));
        grow = rowBase + rg * 4 + 3;
        if (grow < N) hsb4[(size_t)grow * 16 + cg] =
            make_ushort4(f2bf(a3.x), f2bf(a3.y), f2bf(a3.z), f2bf(a3.w));
    }
}

// ---------------------------------------------------------------------------
// Kernel: per-bucket CSR build + dinv + offs. One block per bucket; all csr
// stores land in the block's own contiguous region (single-owner lines).
// ---------------------------------------------------------------------------
__launch_bounds__(256)
__global__ void bucket_csr_kernel(const unsigned* __restrict__ ebuf,
                                  const int* __restrict__ bbase,
                                  int* __restrict__ csr, int* __restrict__ offs,
                                  float* __restrict__ dinv, int N) {
    __shared__ int cnt[BW], sc[BW], cur[BW];
    int t = threadIdx.x;
    int b = blockIdx.x;
    if (t < BW) cnt[t] = 0;
    __syncthreads();
    int beg = bbase[b], end = bbase[b + 1];
    for (int i = beg + t; i < end; i += 256)
        atomicAdd(&cnt[ebuf[i] >> 17], 1);
    __syncthreads();
    if (t < BW) sc[t] = cnt[t];
    __syncthreads();
    for (int d = 1; d < BW; d <<= 1) {
        int u = (t < BW && t >= d) ? sc[t - d] : 0;
        __syncthreads();
        if (t < BW) sc[t] += u;
        __syncthreads();
    }
    int nodeBase = b << BSH;
    if (t < BW) {
        int node = nodeBase + t;
        int ex = beg + sc[t] - cnt[t];
        cur[t] = ex;
        if (node < N) {
            offs[node] = ex;
            dinv[node] = rsqrtf((float)(cnt[t] + 1));
        }
    }
    __syncthreads();
    for (int i = beg + t; i < end; i += 256) {
        unsigned w = ebuf[i];
        int pos = atomicAdd(&cur[w >> 17], 1);
        csr[pos] = (int)(w & 0x1FFFF);
    }
}

// ---------------------------------------------------------------------------
// Kernel: layer-1 PULL aggregation (bf16 gathers, 4 in flight, per-src dinv
// scale in-reg) fused with finalize1 + GEMM2; writes hs2 pre-scaled as bf16.
// 16 nodes/block; 16 lanes per node, lane owns one ushort4 chunk (4 feats).
// ---------------------------------------------------------------------------
__launch_bounds__(256)
__global__ void agg1_gemm2_kernel(const unsigned short* __restrict__ hsb,
                                  const int* __restrict__ csr,
                                  const int* __restrict__ offs, const float* __restrict__ dinv,
                                  const float* __restrict__ b1, const float* __restrict__ W2,
                                  unsigned short* __restrict__ hs2b, int N) {
    __shared__ float W2s[FH * FO];       // 4 KB
    __shared__ float h1s[16][68];        // 68-float row stride (16B-aligned, non-pow2)
    const ushort4* hs4 = (const ushort4*)hsb;   // 16 ushort4 per row
    int tid = threadIdx.x;
    for (int i = tid; i < FH * FO; i += 256) W2s[i] = W2[i];
    int g = tid >> 4, l = tid & 15;
    int n = blockIdx.x * 16 + g;
    if (n < N) {
        float di_n = dinv[n];
        float4 self = bf4_to_f4(hs4[(size_t)n * 16 + l]);
        float4 acc;
        acc.x = self.x * di_n; acc.y = self.y * di_n;
        acc.z = self.z * di_n; acc.w = self.w * di_n;
        int j = offs[n], end = offs[n + 1];
        for (; j + 3 < end; j += 4) {              // 4 gathers in flight
            int s0 = csr[j], s1 = csr[j + 1], s2 = csr[j + 2], s3 = csr[j + 3];
            float d0 = dinv[s0], d1 = dinv[s1], d2 = dinv[s2], d3 = dinv[s3];
            float4 a = bf4_to_f4(hs4[(size_t)s0 * 16 + l]);
            float4 b = bf4_to_f4(hs4[(size_t)s1 * 16 + l]);
            float4 c = bf4_to_f4(hs4[(size_t)s2 * 16 + l]);
            float4 d = bf4_to_f4(hs4[(size_t)s3 * 16 + l]);
            acc.x = fmaf(a.x, d0, fmaf(b.x, d1, fmaf(c.x, d2, fmaf(d.x, d3, acc.x))));
            acc.y = fmaf(a.y, d0, fmaf(b.y, d1, fmaf(c.y, d2, fmaf(d.y, d3, acc.y))));
            acc.z = fmaf(a.z, d0, fmaf(b.z, d1, fmaf(c.z, d2, fmaf(d.z, d3, acc.z))));
            acc.w = fmaf(a.w, d0, fmaf(b.w, d1, fmaf(c.w, d2, fmaf(d.w, d3, acc.w))));
        }
        for (; j < end; ++j) {
            int s0 = csr[j];
            float d0 = dinv[s0];
            float4 a = bf4_to_f4(hs4[(size_t)s0 * 16 + l]);
            acc.x = fmaf(a.x, d0, acc.x); acc.y = fmaf(a.y, d0, acc.y);
            acc.z = fmaf(a.z, d0, acc.z); acc.w = fmaf(a.w, d0, acc.w);
        }
        float4 bb = ((const float4*)b1)[l];
        float4 h;
        h.x = fmaxf(fmaf(di_n, acc.x, bb.x), 0.f);
        h.y = fmaxf(fmaf(di_n, acc.y, bb.y), 0.f);
        h.z = fmaxf(fmaf(di_n, acc.z, bb.z), 0.f);
        h.w = fmaxf(fmaf(di_n, acc.w, bb.w), 0.f);
        *((float4*)&h1s[g][l * 4]) = h;
    }
    __syncthreads();
    int r = tid >> 4, o = tid & 15;     // 16 rows x 16 out-cols
    int n2 = blockIdx.x * 16 + r;
    if (n2 < N) {
        float acc = 0.f;
        #pragma unroll
        for (int jj = 0; jj < FH; ++jj)
            acc = fmaf(h1s[r][jj], W2s[jj * FO + o], acc);
        hs2b[(size_t)n2 * FO + o] = f2bf(acc * dinv[n2]);   // pre-scaled bf16
    }
}

// ---------------------------------------------------------------------------
// Kernel: layer-2 PULL aggregation (4 gathers in flight) + bias + log_softmax.
// hs2b table is 3.2 MB -> fits per-XCD L2; gathers are 2B/lane.
// ---------------------------------------------------------------------------
__launch_bounds__(256)
__global__ void agg2_softmax_kernel(const unsigned short* __restrict__ hs2b,
                                    const int* __restrict__ csr,
                                    const int* __restrict__ offs, const float* __restrict__ dinv,
                                    const float* __restrict__ b2, float* __restrict__ out, int N) {
    int tid = threadIdx.x;
    int g = tid >> 4, o = tid & 15;
    int n = blockIdx.x * 16 + g;
    float v = 0.f;
    if (n < N) {
        float acc = bf2f(hs2b[(size_t)n * 16 + o]);    // self loop (pre-scaled)
        int j = offs[n], end = offs[n + 1];
        for (; j + 3 < end; j += 4) {
            int s0 = csr[j], s1 = csr[j + 1], s2 = csr[j + 2], s3 = csr[j + 3];
            acc += (bf2f(hs2b[(size_t)s0 * 16 + o]) + bf2f(hs2b[(size_t)s1 * 16 + o]))
                 + (bf2f(hs2b[(size_t)s2 * 16 + o]) + bf2f(hs2b[(size_t)s3 * 16 + o]));
        }
        for (; j < end; ++j) acc += bf2f(hs2b[(size_t)csr[j] * 16 + o]);
        v = fmaf(dinv[n], acc, b2[o]);
    }
    float m = v;
    #pragma unroll
    for (int s = 8; s >= 1; s >>= 1) m = fmaxf(m, __shfl_xor(m, s, 64));
    float ex = __expf(v - m);
    float sum = ex;
    #pragma unroll
    for (int s = 8; s >= 1; s >>= 1) sum += __shfl_xor(sum, s, 64);
    if (n < N) out[(size_t)n * FO + o] = v - m - __logf(sum);
}

// ---------------------------------------------------------------------------
extern "C" void kernel_launch(void* const* d_in, const int* in_sizes, int n_in,
                              void* d_out, int out_size, void* d_ws, size_t ws_size,
                              hipStream_t stream) {
    const float* x  = (const float*)d_in[0];
    const int*   ei = (const int*)d_in[1];     // int32
    const float* W1 = (const float*)d_in[2];
    const float* b1 = (const float*)d_in[3];
    const float* W2 = (const float*)d_in[4];
    const float* b2 = (const float*)d_in[5];
    float* out = (float*)d_out;

    const int N = in_sizes[0] / FIN;
    const int E = in_sizes[1] / 2;
    const int NCH  = (E + EPB_HIST - 1) / EPB_HIST;  // hist blocks
    const int NCB  = (E + EPB_BIN - 1) / EPB_BIN;    // binning blocks
    const int NB4  = (N + BW - 1) / BW;              // buckets actually used
    const int G1T  = (N + 63) / 64;                  // gemm 64-row tiles
    const int GA   = (N + 15) / 16;                  // agg blocks

    char* ws = (char*)d_ws;
    size_t off = 0;
    auto alloc = [&](size_t bytes) -> void* {
        off = (off + 255) & ~(size_t)255;
        void* p = ws + off;
        off += bytes;
        return p;
    };
    float*          dinv  = (float*)alloc((size_t)N * 4);               //  0.4 MB
    unsigned short* hsb   = (unsigned short*)alloc((size_t)N * FH * 2); // 12.8 MB
    unsigned short* hs2b  = (unsigned short*)alloc((size_t)N * FO * 2); //  3.2 MB
    int*            offs  = (int*)alloc((size_t)(N + 1) * 4);           //  0.4 MB
    int*            bcnt  = (int*)alloc(NBUCK * 4);
    int*            bbase = (int*)alloc((NBUCK + 1) * 4);
    int*            gcur  = (int*)alloc(NBUCK * 4);
    // ebuf + csr (2*E ints = 12.8 MB): in ws if it fits, else alias the x
    // input buffer (25.6 MB, dead after the gemm phase; harness restores d_in
    // before every launch; ws_size constant -> capture-stable branch).
    unsigned* ebuf;
    int*      csr;
    bool ws_fits = (ws_size >= off + 512 + (size_t)E * 8);
    if (ws_fits) {
        ebuf = (unsigned*)alloc((size_t)E * 4);
        csr  = (int*)     alloc((size_t)E * 4);
    } else {
        ebuf = (unsigned*)x;
        csr  = (int*)x + E;
    }

    hipMemsetAsync(bcnt, 0, NBUCK * 4, stream);

    hist_kernel<<<NCH, 256, 0, stream>>>(ei, E, bcnt);
    bucket_scan_kernel<<<1, NBUCK, 0, stream>>>(bcnt, bbase, gcur, offs, N, E);
    if (ws_fits) {
        // Overlap: gemm blocks + binning blocks in one launch (no aliasing).
        gemm1_binning_kernel<<<G1T + NCB, 256, 0, stream>>>(x, W1, hsb, ei, E,
                                                            gcur, ebuf, N, G1T);
    } else {
        // ebuf aliases x: gemm must fully precede binning.
        gemm1_binning_kernel<<<G1T, 256, 0, stream>>>(x, W1, hsb, ei, E,
                                                      gcur, ebuf, N, G1T);
        binning_kernel<<<NCB, 256, 0, stream>>>(ei, E, gcur, ebuf);
    }
    bucket_csr_kernel<<<NB4, 256, 0, stream>>>(ebuf, bbase, csr, offs, dinv, N);
    agg1_gemm2_kernel<<<GA, 256, 0, stream>>>(hsb, csr, offs, dinv, b1, W2, hs2b, N);
    agg2_softmax_kernel<<<GA, 256, 0, stream>>>(hs2b, csr, offs, dinv, b2, out, N);
}